// Round 1
// baseline (5653.032 us; speedup 1.0000x reference)
//
#include <hip/hip_runtime.h>
#include <math.h>

#define DIM 10

// ---------------------------------------------------------------------------
// Kernel A: per node — zero the x accumulator, and produce the masked h:
//   hdst[n] = active(n, iter) ? hsrc[n] : 0
// For iter 1 hsrc == hdst; we then only need to zero newly-inactive nodes.
// active(n, i) = (depth[n] + i) <= 2
// ---------------------------------------------------------------------------
__global__ void mask_and_zero_kernel(const float* __restrict__ hsrc,
                                     float* __restrict__ hdst,
                                     float* __restrict__ x,
                                     const int* __restrict__ depth,
                                     int iter, int n)
{
    const int stride = gridDim.x * blockDim.x;
    for (int node = blockIdx.x * blockDim.x + threadIdx.x; node < n; node += stride) {
        float2* xd = reinterpret_cast<float2*>(x + (size_t)node * DIM);
        #pragma unroll
        for (int k = 0; k < 5; ++k) xd[k] = make_float2(0.0f, 0.0f);

        const bool active = (depth[node] + iter) <= 2;
        float2* hd = reinterpret_cast<float2*>(hdst + (size_t)node * DIM);
        if (active) {
            if (hsrc != hdst) {
                const float2* hs = reinterpret_cast<const float2*>(hsrc + (size_t)node * DIM);
                #pragma unroll
                for (int k = 0; k < 5; ++k) hd[k] = hs[k];
            }
            // in-place + active: nothing to do
        } else {
            #pragma unroll
            for (int k = 0; k < 5; ++k) hd[k] = make_float2(0.0f, 0.0f);
        }
    }
}

// ---------------------------------------------------------------------------
// Kernel B: edge scatter — x[recv[e]] += hm[send[e]] (10 floats, fp32 atomics).
// Skip the atomics entirely when the gathered vector is all-zero (inactive
// senders are exactly zero; adding zero is always a no-op, so this is safe).
// ---------------------------------------------------------------------------
__global__ void scatter_add_kernel(const int* __restrict__ recv,
                                   const int* __restrict__ send,
                                   const float* __restrict__ hm,
                                   float* __restrict__ x,
                                   int ne)
{
    const int stride = gridDim.x * blockDim.x;
    for (int e = blockIdx.x * blockDim.x + threadIdx.x; e < ne; e += stride) {
        const int s = send[e];
        const float2* hs = reinterpret_cast<const float2*>(hm + (size_t)s * DIM);
        float2 v0 = hs[0], v1 = hs[1], v2 = hs[2], v3 = hs[3], v4 = hs[4];
        const bool nz = (v0.x != 0.0f) | (v0.y != 0.0f) |
                        (v1.x != 0.0f) | (v1.y != 0.0f) |
                        (v2.x != 0.0f) | (v2.y != 0.0f) |
                        (v3.x != 0.0f) | (v3.y != 0.0f) |
                        (v4.x != 0.0f) | (v4.y != 0.0f);
        if (nz) {
            const int r = recv[e];
            float* xr = x + (size_t)r * DIM;
            atomicAdd(xr + 0, v0.x); atomicAdd(xr + 1, v0.y);
            atomicAdd(xr + 2, v1.x); atomicAdd(xr + 3, v1.y);
            atomicAdd(xr + 4, v2.x); atomicAdd(xr + 5, v2.y);
            atomicAdd(xr + 6, v3.x); atomicAdd(xr + 7, v3.y);
            atomicAdd(xr + 8, v4.x); atomicAdd(xr + 9, v4.y);
        }
    }
}

// ---------------------------------------------------------------------------
// Kernel C: per-node GRU update (in place on h). Only writes active nodes;
// inactive nodes were already zeroed by kernel A.
//   z = sigmoid(x@Wz^T + h@Uz^T + (bz+buz))
//   r = sigmoid(x@Wr^T + h@Ur^T + (br+bur))
//   h = z*h + (1-z)*tanh(x@Wh^T + (r*h)@Uh^T + (bh+buh))
// ---------------------------------------------------------------------------
__global__ void gru_update_kernel(const float* __restrict__ x,
                                  float* __restrict__ h,
                                  const int* __restrict__ depth,
                                  int iter, int n,
                                  const float* __restrict__ Wz, const float* __restrict__ bz,
                                  const float* __restrict__ Uz, const float* __restrict__ buz,
                                  const float* __restrict__ Wr, const float* __restrict__ br,
                                  const float* __restrict__ Ur, const float* __restrict__ bur,
                                  const float* __restrict__ Wh, const float* __restrict__ bh,
                                  const float* __restrict__ Uh, const float* __restrict__ buh)
{
    // LDS-resident weights: 6 matrices (100 each) + 3 combined biases (10 each)
    __shared__ float sW[6][100];
    __shared__ float sb[3][10];
    const int t = threadIdx.x;
    if (t < 100) {
        sW[0][t] = Wz[t]; sW[1][t] = Uz[t];
        sW[2][t] = Wr[t]; sW[3][t] = Ur[t];
        sW[4][t] = Wh[t]; sW[5][t] = Uh[t];
    }
    if (t < 10) {
        sb[0][t] = bz[t] + buz[t];
        sb[1][t] = br[t] + bur[t];
        sb[2][t] = bh[t] + buh[t];
    }
    __syncthreads();

    const int stride = gridDim.x * blockDim.x;
    for (int node = blockIdx.x * blockDim.x + t; node < n; node += stride) {
        if (depth[node] + iter > 2) continue;   // inactive: already zero, skip

        float xv[DIM], hv[DIM];
        const float2* xp = reinterpret_cast<const float2*>(x + (size_t)node * DIM);
        const float2* hp = reinterpret_cast<const float2*>(h + (size_t)node * DIM);
        #pragma unroll
        for (int k = 0; k < 5; ++k) {
            float2 a = xp[k]; xv[2 * k] = a.x; xv[2 * k + 1] = a.y;
            float2 b = hp[k]; hv[2 * k] = b.x; hv[2 * k + 1] = b.y;
        }

        float zz[DIM], rr[DIM];
        #pragma unroll
        for (int i = 0; i < DIM; ++i) {
            float az = sb[0][i];
            float ar = sb[1][i];
            #pragma unroll
            for (int j = 0; j < DIM; ++j) {
                az = fmaf(xv[j], sW[0][i * DIM + j], az);
                az = fmaf(hv[j], sW[1][i * DIM + j], az);
                ar = fmaf(xv[j], sW[2][i * DIM + j], ar);
                ar = fmaf(hv[j], sW[3][i * DIM + j], ar);
            }
            zz[i] = 1.0f / (1.0f + __expf(-az));
            rr[i] = 1.0f / (1.0f + __expf(-ar));
        }

        float rh[DIM];
        #pragma unroll
        for (int j = 0; j < DIM; ++j) rh[j] = rr[j] * hv[j];

        float outv[DIM];
        #pragma unroll
        for (int i = 0; i < DIM; ++i) {
            float ah = sb[2][i];
            #pragma unroll
            for (int j = 0; j < DIM; ++j) {
                ah = fmaf(xv[j], sW[4][i * DIM + j], ah);
                ah = fmaf(rh[j], sW[5][i * DIM + j], ah);
            }
            float th = tanhf(ah);
            outv[i] = zz[i] * hv[i] + (1.0f - zz[i]) * th;
        }

        float2* hw = reinterpret_cast<float2*>(h + (size_t)node * DIM);
        #pragma unroll
        for (int k = 0; k < 5; ++k) hw[k] = make_float2(outv[2 * k], outv[2 * k + 1]);
    }
}

extern "C" void kernel_launch(void* const* d_in, const int* in_sizes, int n_in,
                              void* d_out, int out_size, void* d_ws, size_t ws_size,
                              hipStream_t stream) {
    const float* h_in  = (const float*)d_in[0];
    const int*   edges = (const int*)d_in[1];
    const int*   depth = (const int*)d_in[2];
    const float* Wz  = (const float*)d_in[3];
    const float* bz  = (const float*)d_in[4];
    const float* Uz  = (const float*)d_in[5];
    const float* buz = (const float*)d_in[6];
    const float* Wr  = (const float*)d_in[7];
    const float* br  = (const float*)d_in[8];
    const float* Ur  = (const float*)d_in[9];
    const float* bur = (const float*)d_in[10];
    const float* Wh  = (const float*)d_in[11];
    const float* bh  = (const float*)d_in[12];
    const float* Uh  = (const float*)d_in[13];
    const float* buh = (const float*)d_in[14];

    const int n  = in_sizes[0] / DIM;       // 500,000 nodes
    const int ne = in_sizes[1] / 2;         // 8,000,000 edges
    const int* recv = edges;
    const int* send = edges + ne;

    float* h = (float*)d_out;               // h lives in d_out (20 MB)
    float* x = (float*)d_ws;                // x accumulator in workspace (20 MB)

    const int BLK = 256;
    const int node_blocks = (n + BLK - 1) / BLK;      // 1954
    const int edge_blocks = (ne + BLK - 1) / BLK;     // 31250

    // -------- iteration 0 (active: depth <= 2) --------
    mask_and_zero_kernel<<<node_blocks, BLK, 0, stream>>>(h_in, h, x, depth, 0, n);
    scatter_add_kernel<<<edge_blocks, BLK, 0, stream>>>(recv, send, h, x, ne);
    gru_update_kernel<<<node_blocks, BLK, 0, stream>>>(x, h, depth, 0, n,
        Wz, bz, Uz, buz, Wr, br, Ur, bur, Wh, bh, Uh, buh);

    // -------- iteration 1 (active: depth <= 1) --------
    mask_and_zero_kernel<<<node_blocks, BLK, 0, stream>>>(h, h, x, depth, 1, n);
    scatter_add_kernel<<<edge_blocks, BLK, 0, stream>>>(recv, send, h, x, ne);
    gru_update_kernel<<<node_blocks, BLK, 0, stream>>>(x, h, depth, 1, n,
        Wz, bz, Uz, buz, Wr, br, Ur, bur, Wh, bh, Uh, buh);
}

// Round 2
// 1434.895 us; speedup vs baseline: 3.9397x; 3.9397x over previous
//
#include <hip/hip_runtime.h>
#include <math.h>

#define DIM 10

// ---------------------------------------------------------------------------
// Kernel A: per node — zero the x accumulator, and produce the masked h:
//   hdst[n] = active(n, iter) ? hsrc[n] : 0
// active(n, i) = (depth[n] + i) <= 2
// ---------------------------------------------------------------------------
__global__ void mask_and_zero_kernel(const float* __restrict__ hsrc,
                                     float* __restrict__ hdst,
                                     float* __restrict__ x,
                                     const int* __restrict__ depth,
                                     int iter, int n)
{
    const int stride = gridDim.x * blockDim.x;
    for (int node = blockIdx.x * blockDim.x + threadIdx.x; node < n; node += stride) {
        float2* xd = reinterpret_cast<float2*>(x + (size_t)node * DIM);
        #pragma unroll
        for (int k = 0; k < 5; ++k) xd[k] = make_float2(0.0f, 0.0f);

        const bool active = (depth[node] + iter) <= 2;
        float2* hd = reinterpret_cast<float2*>(hdst + (size_t)node * DIM);
        if (active) {
            if (hsrc != hdst) {
                const float2* hs = reinterpret_cast<const float2*>(hsrc + (size_t)node * DIM);
                #pragma unroll
                for (int k = 0; k < 5; ++k) hd[k] = hs[k];
            }
        } else {
            #pragma unroll
            for (int k = 0; k < 5; ++k) hd[k] = make_float2(0.0f, 0.0f);
        }
    }
}

// ---------------------------------------------------------------------------
// Kernel B: edge scatter — one thread per (edge, component).
//   x[recv[e]*10 + c] += hm[send[e]*10 + c]
// Lanes 10e..10e+9 cover one edge -> consecutive atomic addresses within a
// wave land in the same cache line (fewer line transactions at the atomic
// unit). unsafeAtomicAdd emits hardware global_atomic_add_f32 (non-returning,
// no CAS loop). Skip exact-zero components (adding 0 is a no-op; inactive
// senders are exactly zero).
// ---------------------------------------------------------------------------
__global__ void scatter_add_kernel(const int* __restrict__ recv,
                                   const int* __restrict__ send,
                                   const float* __restrict__ hm,
                                   float* __restrict__ x,
                                   int nwork)   // nwork = ne * DIM
{
    const int tid = blockIdx.x * blockDim.x + threadIdx.x;
    if (tid >= nwork) return;
    const int e = tid / DIM;
    const int c = tid - e * DIM;
    const int s = send[e];
    const float v = hm[(size_t)s * DIM + c];
    if (v != 0.0f) {
        const int r = recv[e];
        unsafeAtomicAdd(x + (size_t)r * DIM + c, v);
    }
}

// ---------------------------------------------------------------------------
// Kernel C: per-node GRU update (in place on h). Only writes active nodes;
// inactive nodes were already zeroed by kernel A.
// ---------------------------------------------------------------------------
__global__ void gru_update_kernel(const float* __restrict__ x,
                                  float* __restrict__ h,
                                  const int* __restrict__ depth,
                                  int iter, int n,
                                  const float* __restrict__ Wz, const float* __restrict__ bz,
                                  const float* __restrict__ Uz, const float* __restrict__ buz,
                                  const float* __restrict__ Wr, const float* __restrict__ br,
                                  const float* __restrict__ Ur, const float* __restrict__ bur,
                                  const float* __restrict__ Wh, const float* __restrict__ bh,
                                  const float* __restrict__ Uh, const float* __restrict__ buh)
{
    __shared__ float sW[6][100];
    __shared__ float sb[3][10];
    const int t = threadIdx.x;
    if (t < 100) {
        sW[0][t] = Wz[t]; sW[1][t] = Uz[t];
        sW[2][t] = Wr[t]; sW[3][t] = Ur[t];
        sW[4][t] = Wh[t]; sW[5][t] = Uh[t];
    }
    if (t < 10) {
        sb[0][t] = bz[t] + buz[t];
        sb[1][t] = br[t] + bur[t];
        sb[2][t] = bh[t] + buh[t];
    }
    __syncthreads();

    const int stride = gridDim.x * blockDim.x;
    for (int node = blockIdx.x * blockDim.x + t; node < n; node += stride) {
        if (depth[node] + iter > 2) continue;   // inactive: already zero, skip

        float xv[DIM], hv[DIM];
        const float2* xp = reinterpret_cast<const float2*>(x + (size_t)node * DIM);
        const float2* hp = reinterpret_cast<const float2*>(h + (size_t)node * DIM);
        #pragma unroll
        for (int k = 0; k < 5; ++k) {
            float2 a = xp[k]; xv[2 * k] = a.x; xv[2 * k + 1] = a.y;
            float2 b = hp[k]; hv[2 * k] = b.x; hv[2 * k + 1] = b.y;
        }

        float zz[DIM], rr[DIM];
        #pragma unroll
        for (int i = 0; i < DIM; ++i) {
            float az = sb[0][i];
            float ar = sb[1][i];
            #pragma unroll
            for (int j = 0; j < DIM; ++j) {
                az = fmaf(xv[j], sW[0][i * DIM + j], az);
                az = fmaf(hv[j], sW[1][i * DIM + j], az);
                ar = fmaf(xv[j], sW[2][i * DIM + j], ar);
                ar = fmaf(hv[j], sW[3][i * DIM + j], ar);
            }
            zz[i] = 1.0f / (1.0f + __expf(-az));
            rr[i] = 1.0f / (1.0f + __expf(-ar));
        }

        float rh[DIM];
        #pragma unroll
        for (int j = 0; j < DIM; ++j) rh[j] = rr[j] * hv[j];

        float outv[DIM];
        #pragma unroll
        for (int i = 0; i < DIM; ++i) {
            float ah = sb[2][i];
            #pragma unroll
            for (int j = 0; j < DIM; ++j) {
                ah = fmaf(xv[j], sW[4][i * DIM + j], ah);
                ah = fmaf(rh[j], sW[5][i * DIM + j], ah);
            }
            float th = tanhf(ah);
            outv[i] = zz[i] * hv[i] + (1.0f - zz[i]) * th;
        }

        float2* hw = reinterpret_cast<float2*>(h + (size_t)node * DIM);
        #pragma unroll
        for (int k = 0; k < 5; ++k) hw[k] = make_float2(outv[2 * k], outv[2 * k + 1]);
    }
}

extern "C" void kernel_launch(void* const* d_in, const int* in_sizes, int n_in,
                              void* d_out, int out_size, void* d_ws, size_t ws_size,
                              hipStream_t stream) {
    const float* h_in  = (const float*)d_in[0];
    const int*   edges = (const int*)d_in[1];
    const int*   depth = (const int*)d_in[2];
    const float* Wz  = (const float*)d_in[3];
    const float* bz  = (const float*)d_in[4];
    const float* Uz  = (const float*)d_in[5];
    const float* buz = (const float*)d_in[6];
    const float* Wr  = (const float*)d_in[7];
    const float* br  = (const float*)d_in[8];
    const float* Ur  = (const float*)d_in[9];
    const float* bur = (const float*)d_in[10];
    const float* Wh  = (const float*)d_in[11];
    const float* bh  = (const float*)d_in[12];
    const float* Uh  = (const float*)d_in[13];
    const float* buh = (const float*)d_in[14];

    const int n  = in_sizes[0] / DIM;       // 500,000 nodes
    const int ne = in_sizes[1] / 2;         // 8,000,000 edges
    const int* recv = edges;
    const int* send = edges + ne;

    float* h = (float*)d_out;               // h lives in d_out (20 MB)
    float* x = (float*)d_ws;                // x accumulator in workspace (20 MB)

    const int BLK = 256;
    const int node_blocks = (n + BLK - 1) / BLK;          // 1954
    const int nwork = ne * DIM;                           // 80,000,000
    const int edge_blocks = (nwork + BLK - 1) / BLK;      // 312,500

    // -------- iteration 0 (active: depth <= 2) --------
    mask_and_zero_kernel<<<node_blocks, BLK, 0, stream>>>(h_in, h, x, depth, 0, n);
    scatter_add_kernel<<<edge_blocks, BLK, 0, stream>>>(recv, send, h, x, nwork);
    gru_update_kernel<<<node_blocks, BLK, 0, stream>>>(x, h, depth, 0, n,
        Wz, bz, Uz, buz, Wr, br, Ur, bur, Wh, bh, Uh, buh);

    // -------- iteration 1 (active: depth <= 1) --------
    mask_and_zero_kernel<<<node_blocks, BLK, 0, stream>>>(h, h, x, depth, 1, n);
    scatter_add_kernel<<<edge_blocks, BLK, 0, stream>>>(recv, send, h, x, nwork);
    gru_update_kernel<<<node_blocks, BLK, 0, stream>>>(x, h, depth, 1, n,
        Wz, bz, Uz, buz, Wr, br, Ur, bur, Wh, bh, Uh, buh);
}

// Round 3
// 987.527 us; speedup vs baseline: 5.7244x; 1.4530x over previous
//
#include <hip/hip_runtime.h>
#include <math.h>

#define DIM 10
#define NTILE 256

// ---------------------------------------------------------------------------
// zero x accumulator (includes pad slots; coalesced float4 stores)
// ---------------------------------------------------------------------------
__global__ void zero_x_kernel(float4* __restrict__ x4, int tot4) {
    int i = blockIdx.x * blockDim.x + threadIdx.x;
    if (i < tot4) x4[i] = make_float4(0.0f, 0.0f, 0.0f, 0.0f);
}

// ---------------------------------------------------------------------------
// iter-0 mask: read h_in (stride 10, coalesced via LDS), zero inactive nodes,
// write to working h buffer (stride HS, coalesced flush, pads = 0).
// active(iter 0) = depth <= 2
// ---------------------------------------------------------------------------
template<int HS>
__global__ void mask0_kernel(const float* __restrict__ hsrc,   // stride DIM
                             float* __restrict__ hdst,         // stride HS
                             const int* __restrict__ depth,
                             int n)
{
    __shared__ float sh[NTILE * 11];
    const int t = threadIdx.x;
    const int base = blockIdx.x * NTILE;

    // stage input tile (NTILE*DIM floats, coalesced scalar)
    const long gbase = (long)base * DIM;
    const long glim  = (long)n * DIM;
    for (int idx = t; idx < NTILE * DIM; idx += NTILE) {
        long g = gbase + idx;
        float v = (g < glim) ? hsrc[g] : 0.0f;
        sh[(idx / DIM) * 11 + (idx % DIM)] = v;
    }
    __syncthreads();

    const int node = base + t;
    bool inactive = true;
    if (node < n) inactive = (depth[node] > 2);     // iter 0
    if (inactive) {
        #pragma unroll
        for (int c = 0; c < DIM; ++c) sh[t * 11 + c] = 0.0f;
    }
    __syncthreads();

    // flush NTILE*HS floats coalesced (pad components -> 0)
    const long obase = (long)base * HS;
    const long olim  = (long)n * HS;
    for (int idx = t; idx < NTILE * HS; idx += NTILE) {
        long g = obase + idx;
        if (g < olim) {
            int nl = idx / HS, c = idx % HS;
            hdst[g] = (c < DIM) ? sh[nl * 11 + c] : 0.0f;
        }
    }
}

// ---------------------------------------------------------------------------
// iter-1 mask (in place): zero nodes that just became inactive.
// active(iter 1) = depth <= 1
// ---------------------------------------------------------------------------
template<int HS>
__global__ void mask1_kernel(float* __restrict__ h,
                             const int* __restrict__ depth,
                             int tot)     // n * HS
{
    int i = blockIdx.x * blockDim.x + threadIdx.x;
    if (i >= tot) return;
    int node = i / HS;
    if (depth[node] > 1) h[i] = 0.0f;
}

// ---------------------------------------------------------------------------
// edge scatter: thread per (edge, component); hardware non-returning atomics.
// With HS=XS=16 each node record is one aligned 64B line.
// ---------------------------------------------------------------------------
template<int XS, int HS>
__global__ void scatter_add_kernel(const int* __restrict__ recv,
                                   const int* __restrict__ send,
                                   const float* __restrict__ hm,  // stride HS
                                   float* __restrict__ x,         // stride XS
                                   int ne)
{
    const int tid = blockIdx.x * blockDim.x + threadIdx.x;
    const int e = tid / DIM;
    if (e >= ne) return;
    const int c = tid - e * DIM;
    const int s = send[e];
    const float v = hm[(long)s * HS + c];
    if (v != 0.0f) {
        const int r = recv[e];
        unsafeAtomicAdd(x + (long)r * XS + c, v);
    }
}

// ---------------------------------------------------------------------------
// GRU update, LDS tile-staged. out = active ? gru(x,h) : h   (h==0 inactive).
// Writes `out` with runtime stride OS (16 = padded working h, 10 = d_out).
// ---------------------------------------------------------------------------
template<int XS, int HS>
__global__ void gru_kernel(const float* __restrict__ x,
                           const float* __restrict__ h,
                           float* __restrict__ out, int OS,
                           const int* __restrict__ depth, int iter, int n,
                           const float* __restrict__ Wz, const float* __restrict__ bz,
                           const float* __restrict__ Uz, const float* __restrict__ buz,
                           const float* __restrict__ Wr, const float* __restrict__ br,
                           const float* __restrict__ Ur, const float* __restrict__ bur,
                           const float* __restrict__ Wh, const float* __restrict__ bh,
                           const float* __restrict__ Uh, const float* __restrict__ buh)
{
    __shared__ float sx[NTILE * 17];
    __shared__ float shh[NTILE * 17];
    __shared__ float sW[6][100];
    __shared__ float sb[3][10];

    const int t = threadIdx.x;
    if (t < 100) {
        sW[0][t] = Wz[t]; sW[1][t] = Uz[t];
        sW[2][t] = Wr[t]; sW[3][t] = Ur[t];
        sW[4][t] = Wh[t]; sW[5][t] = Uh[t];
    }
    if (t < 10) {
        sb[0][t] = bz[t] + buz[t];
        sb[1][t] = br[t] + bur[t];
        sb[2][t] = bh[t] + buh[t];
    }

    const int base = blockIdx.x * NTILE;

    // ---- stage x tile (float4, coalesced) ----
    {
        const int tile4 = NTILE * XS / 4;
        const long g4base = (long)base * XS / 4;
        const long g4lim  = (long)n * XS / 4;
        const float4* xg = reinterpret_cast<const float4*>(x);
        for (int i4 = t; i4 < tile4; i4 += NTILE) {
            long g = g4base + i4;
            if (g < g4lim) {
                float4 v = xg[g];
                float vv[4] = {v.x, v.y, v.z, v.w};
                int f = i4 * 4;
                int nl = f / XS, c = f % XS;
                #pragma unroll
                for (int k = 0; k < 4; ++k) {
                    sx[nl * 17 + c] = vv[k];
                    if (++c == XS) { c = 0; ++nl; }
                }
            }
        }
    }
    // ---- stage h tile (float4, coalesced) ----
    {
        const int tile4 = NTILE * HS / 4;
        const long g4base = (long)base * HS / 4;
        const long g4lim  = (long)n * HS / 4;
        const float4* hg = reinterpret_cast<const float4*>(h);
        for (int i4 = t; i4 < tile4; i4 += NTILE) {
            long g = g4base + i4;
            if (g < g4lim) {
                float4 v = hg[g];
                float vv[4] = {v.x, v.y, v.z, v.w};
                int f = i4 * 4;
                int nl = f / HS, c = f % HS;
                #pragma unroll
                for (int k = 0; k < 4; ++k) {
                    shh[nl * 17 + c] = vv[k];
                    if (++c == HS) { c = 0; ++nl; }
                }
            }
        }
    }
    __syncthreads();

    const int node = base + t;
    const bool valid = node < n;
    const bool active = valid && (depth[node] + iter <= 2);

    float xv[DIM], hv[DIM], outv[DIM];
    #pragma unroll
    for (int j = 0; j < DIM; ++j) {
        xv[j] = sx[t * 17 + j];
        hv[j] = shh[t * 17 + j];
    }

    if (active) {
        float zz[DIM], rr[DIM];
        #pragma unroll
        for (int i = 0; i < DIM; ++i) {
            float az = sb[0][i];
            float ar = sb[1][i];
            #pragma unroll
            for (int j = 0; j < DIM; ++j) {
                az = fmaf(xv[j], sW[0][i * DIM + j], az);
                az = fmaf(hv[j], sW[1][i * DIM + j], az);
                ar = fmaf(xv[j], sW[2][i * DIM + j], ar);
                ar = fmaf(hv[j], sW[3][i * DIM + j], ar);
            }
            zz[i] = 1.0f / (1.0f + __expf(-az));
            rr[i] = 1.0f / (1.0f + __expf(-ar));
        }
        float rh[DIM];
        #pragma unroll
        for (int j = 0; j < DIM; ++j) rh[j] = rr[j] * hv[j];
        #pragma unroll
        for (int i = 0; i < DIM; ++i) {
            float ah = sb[2][i];
            #pragma unroll
            for (int j = 0; j < DIM; ++j) {
                ah = fmaf(xv[j], sW[4][i * DIM + j], ah);
                ah = fmaf(rh[j], sW[5][i * DIM + j], ah);
            }
            float th = tanhf(ah);
            outv[i] = zz[i] * hv[i] + (1.0f - zz[i]) * th;
        }
    } else {
        #pragma unroll
        for (int i = 0; i < DIM; ++i) outv[i] = hv[i];   // inactive: h already 0
    }

    __syncthreads();   // everyone done reading sx before we overwrite it
    #pragma unroll
    for (int i = 0; i < DIM; ++i) sx[t * 17 + i] = outv[i];
    __syncthreads();

    // ---- flush NTILE*OS floats coalesced (pad components -> 0) ----
    const long obase = (long)base * OS;
    const long olim  = (long)n * OS;
    for (int idx = t; idx < NTILE * OS; idx += NTILE) {
        long g = obase + idx;
        if (g < olim) {
            int nl = idx / OS, c = idx % OS;
            out[g] = (c < DIM) ? sx[nl * 17 + c] : 0.0f;
        }
    }
}

// ---------------------------------------------------------------------------
template<int XS, int HS>
static void run_pipeline(const float* h_in, const int* recv, const int* send,
                         const int* depth, float* x, float* hbuf, float* d_out,
                         int n, int ne, hipStream_t stream,
                         const float* Wz, const float* bz, const float* Uz, const float* buz,
                         const float* Wr, const float* br, const float* Ur, const float* bur,
                         const float* Wh, const float* bh, const float* Uh, const float* buh)
{
    const int BLK = 256;
    const int node_blocks = (n + NTILE - 1) / NTILE;
    const int x_tot4 = n * XS / 4;
    const int xz_blocks = (x_tot4 + BLK - 1) / BLK;
    const int edge_work = ne * DIM;
    const int edge_blocks = (edge_work + BLK - 1) / BLK;
    const int h_tot = n * HS;
    const int m1_blocks = (h_tot + BLK - 1) / BLK;

    // -------- iteration 0 (active: depth <= 2) --------
    zero_x_kernel<<<xz_blocks, BLK, 0, stream>>>((float4*)x, x_tot4);
    mask0_kernel<HS><<<node_blocks, NTILE, 0, stream>>>(h_in, hbuf, depth, n);
    scatter_add_kernel<XS, HS><<<edge_blocks, BLK, 0, stream>>>(recv, send, hbuf, x, ne);
    gru_kernel<XS, HS><<<node_blocks, NTILE, 0, stream>>>(x, hbuf, hbuf, HS, depth, 0, n,
        Wz, bz, Uz, buz, Wr, br, Ur, bur, Wh, bh, Uh, buh);

    // -------- iteration 1 (active: depth <= 1) --------
    zero_x_kernel<<<xz_blocks, BLK, 0, stream>>>((float4*)x, x_tot4);
    mask1_kernel<HS><<<m1_blocks, BLK, 0, stream>>>(hbuf, depth, h_tot);
    scatter_add_kernel<XS, HS><<<edge_blocks, BLK, 0, stream>>>(recv, send, hbuf, x, ne);
    gru_kernel<XS, HS><<<node_blocks, NTILE, 0, stream>>>(x, hbuf, d_out, DIM, depth, 1, n,
        Wz, bz, Uz, buz, Wr, br, Ur, bur, Wh, bh, Uh, buh);
}

extern "C" void kernel_launch(void* const* d_in, const int* in_sizes, int n_in,
                              void* d_out, int out_size, void* d_ws, size_t ws_size,
                              hipStream_t stream) {
    const float* h_in  = (const float*)d_in[0];
    const int*   edges = (const int*)d_in[1];
    const int*   depth = (const int*)d_in[2];
    const float* Wz  = (const float*)d_in[3];
    const float* bz  = (const float*)d_in[4];
    const float* Uz  = (const float*)d_in[5];
    const float* buz = (const float*)d_in[6];
    const float* Wr  = (const float*)d_in[7];
    const float* br  = (const float*)d_in[8];
    const float* Ur  = (const float*)d_in[9];
    const float* bur = (const float*)d_in[10];
    const float* Wh  = (const float*)d_in[11];
    const float* bh  = (const float*)d_in[12];
    const float* Uh  = (const float*)d_in[13];
    const float* buh = (const float*)d_in[14];

    const int n  = in_sizes[0] / DIM;       // 500,000
    const int ne = in_sizes[1] / 2;         // 8,000,000
    const int* recv = edges;
    const int* send = edges + ne;

    const size_t padded_need = (size_t)n * 16 * sizeof(float) * 2;   // x + h, 64 MB

    if (ws_size >= padded_need) {
        float* x    = (float*)d_ws;                 // [n*16]
        float* hbuf = (float*)d_ws + (size_t)n * 16;
        run_pipeline<16, 16>(h_in, recv, send, depth, x, hbuf, (float*)d_out,
                             n, ne, stream,
                             Wz, bz, Uz, buz, Wr, br, Ur, bur, Wh, bh, Uh, buh);
    } else {
        // fallback: unpadded, h lives in d_out (round-2 layout)
        float* x    = (float*)d_ws;                 // [n*10]
        float* hbuf = (float*)d_out;
        run_pipeline<10, 10>(h_in, recv, send, depth, x, hbuf, (float*)d_out,
                             n, ne, stream,
                             Wz, bz, Uz, buz, Wr, br, Ur, bur, Wh, bh, Uh, buh);
    }
}